// Round 5
// baseline (120.213 us; speedup 1.0000x reference)
//
#include <hip/hip_runtime.h>

// COLMAP reprojection residual.
// R4 evidence: pose-in-LDS cut 167->105us (request-path theory confirmed).
// Remaining gap vs ~35us stream floor: latency-bound point gather — each wave
// has only ~1 divergent gather in flight per grid-stride iteration.
// R5 fix: unroll x4 — issue 4 independent index loads + 4 point gathers + 4
// p2d loads per iteration, then compute/store 4. 4x MLP per wave.

typedef float f2_t __attribute__((ext_vector_type(2)));

#define NCAM_MAX 2032   // 8 arrays * 2032 * 4B = 63.5 KB static LDS
#define UNROLL 4

__global__ __launch_bounds__(256) void prep_pts(
    const float* __restrict__ pts3, float4* __restrict__ pts4, int n)
{
    int i = blockIdx.x * blockDim.x + threadIdx.x;
    if (i >= n) return;
    const float* p = pts3 + (long)i * 3;
    pts4[i] = make_float4(p[0], p[1], p[2], 0.0f);
}

__device__ __forceinline__ void compute_one(
    float px, float py, float pz,
    float qx, float qy, float qz,
    float tx, float ty, float tz,
    float fl, unsigned kk,
    f2_t o, f2_t* r)
{
    float qw = sqrtf(fmaxf(0.0f, 1.0f - (qx*qx + qy*qy + qz*qz)));
    float ux = qy*pz - qz*py;
    float uy = qz*px - qx*pz;
    float uz = qx*py - qy*px;
    float wx = ux + qw*px;
    float wy = uy + qw*py;
    float wz = uz + qw*pz;
    float cx = qy*wz - qz*wy;
    float cy = qz*wx - qx*wz;
    float cz = qx*wy - qy*wx;
    float Px = px + 2.0f*cx + tx;
    float Py = py + 2.0f*cy + ty;
    float Pz = pz + 2.0f*cz + tz;
    float invz = 1.0f / Pz;
    float u = Px * invz;
    float v = Py * invz;
    float k1 = __uint_as_float(kk << 16);
    float k2 = __uint_as_float(kk & 0xffff0000u);
    float n = u*u + v*v;
    float d = 1.0f + k1*n + k2*n*n;
    float s = d * fl;
    r->x = u*s - o.x;
    r->y = v*s - o.y;
}

__global__ __launch_bounds__(1024) void reproj4_kernel(
    const float* __restrict__ p2d,
    const int* __restrict__ cidx,
    const int* __restrict__ pidx,
    const float* __restrict__ pose,
    const float4* __restrict__ pts4,
    float* __restrict__ out,
    int M, int n_imgs)
{
    __shared__ float s_tx[NCAM_MAX], s_ty[NCAM_MAX], s_tz[NCAM_MAX];
    __shared__ float s_qx[NCAM_MAX], s_qy[NCAM_MAX], s_qz[NCAM_MAX];
    __shared__ float s_fl[NCAM_MAX];
    __shared__ unsigned s_kk[NCAM_MAX];

    for (int r = threadIdx.x; r < n_imgs; r += blockDim.x) {
        const float* c = pose + (long)r * 10;
        float tx = c[0], ty = c[1], tz = c[2];
        float qx = c[3], qy = c[4], qz = c[5], qw = c[6];
        float fl = c[7], k1 = c[8], k2 = c[9];
        float inv = rsqrtf(qx*qx + qy*qy + qz*qz + qw*qw);
        if (qw < 0.0f) inv = -inv;
        qx *= inv; qy *= inv; qz *= inv;
        s_tx[r] = tx; s_ty[r] = ty; s_tz[r] = tz;
        s_qx[r] = qx; s_qy[r] = qy; s_qz[r] = qz;
        s_fl[r] = fl;
        unsigned b1 = (__float_as_uint(k1) + 0x8000u) >> 16;
        unsigned b2 = (__float_as_uint(k2) + 0x8000u) >> 16;
        s_kk[r] = (b1 & 0xffffu) | ((b2 & 0xffffu) << 16);
    }
    __syncthreads();

    int tid = blockIdx.x * blockDim.x + threadIdx.x;
    int stride = gridDim.x * blockDim.x;
    long step = (long)stride * UNROLL;

    for (long base = tid; base < M; base += step) {
        if (base + (long)(UNROLL - 1) * stride < M) {
            // fast path: all 4 in range — batch loads for MLP
            int ci[UNROLL], pi[UNROLL];
            #pragma unroll
            for (int k = 0; k < UNROLL; k++) {
                long i = base + (long)k * stride;
                ci[k] = __builtin_nontemporal_load(cidx + i);
                pi[k] = __builtin_nontemporal_load(pidx + i);
            }
            float4 p[UNROLL];
            f2_t o[UNROLL];
            #pragma unroll
            for (int k = 0; k < UNROLL; k++) {
                p[k] = pts4[pi[k]];
                o[k] = __builtin_nontemporal_load((const f2_t*)p2d + (base + (long)k * stride));
            }
            #pragma unroll
            for (int k = 0; k < UNROLL; k++) {
                int c = ci[k];
                f2_t r;
                compute_one(p[k].x, p[k].y, p[k].z,
                            s_qx[c], s_qy[c], s_qz[c],
                            s_tx[c], s_ty[c], s_tz[c],
                            s_fl[c], s_kk[c], o[k], &r);
                __builtin_nontemporal_store(r, (f2_t*)out + (base + (long)k * stride));
            }
        } else {
            for (int k = 0; k < UNROLL; k++) {
                long i = base + (long)k * stride;
                if (i >= M) break;
                int c = __builtin_nontemporal_load(cidx + i);
                int pi1 = __builtin_nontemporal_load(pidx + i);
                float4 p = pts4[pi1];
                f2_t o = __builtin_nontemporal_load((const f2_t*)p2d + i);
                f2_t r;
                compute_one(p.x, p.y, p.z,
                            s_qx[c], s_qy[c], s_qz[c],
                            s_tx[c], s_ty[c], s_tz[c],
                            s_fl[c], s_kk[c], o, &r);
                __builtin_nontemporal_store(r, (f2_t*)out + i);
            }
        }
    }
}

// Fallback: direct per-obs kernel (ws too small or too many cameras).
__global__ __launch_bounds__(256) void reproj_direct_kernel(
    const float2* __restrict__ p2d,
    const int* __restrict__ cidx,
    const int* __restrict__ pidx,
    const float* __restrict__ pose,
    const float* __restrict__ pts3,
    float2* __restrict__ out,
    int M)
{
    int i = blockIdx.x * blockDim.x + threadIdx.x;
    if (i >= M) return;
    int ci = cidx[i];
    int pi = pidx[i];
    const float* cam = pose + (long)ci * 10;
    float tx = cam[0], ty = cam[1], tz = cam[2];
    float qx = cam[3], qy = cam[4], qz = cam[5], qw = cam[6];
    float f  = cam[7], k1 = cam[8], k2 = cam[9];
    float inv = rsqrtf(qx*qx + qy*qy + qz*qz + qw*qw);
    qx *= inv; qy *= inv; qz *= inv; qw *= inv;
    const float* pp = pts3 + (long)pi * 3;
    float px = pp[0], py = pp[1], pz = pp[2];
    float ux = qy*pz - qz*py;
    float uy = qz*px - qx*pz;
    float uz = qx*py - qy*px;
    float wx = ux + qw*px;
    float wy = uy + qw*py;
    float wz = uz + qw*pz;
    float cx = qy*wz - qz*wy;
    float cy = qz*wx - qx*wz;
    float cz = qx*wy - qy*wx;
    float Px = px + 2.0f*cx + tx;
    float Py = py + 2.0f*cy + ty;
    float Pz = pz + 2.0f*cz + tz;
    float invz = 1.0f / Pz;
    float u = Px * invz;
    float v = Py * invz;
    float n = u*u + v*v;
    float d = 1.0f + k1*n + k2*n*n;
    float s = d * f;
    float2 o = p2d[i];
    out[i] = make_float2(u*s - o.x, v*s - o.y);
}

extern "C" void kernel_launch(void* const* d_in, const int* in_sizes, int n_in,
                              void* d_out, int out_size, void* d_ws, size_t ws_size,
                              hipStream_t stream) {
    const float* p2d  = (const float*)d_in[0];
    const int*   cidx = (const int*)d_in[1];
    const int*   pidx = (const int*)d_in[2];
    const float* pose = (const float*)d_in[3];
    const float* pts3 = (const float*)d_in[4];

    int M      = in_sizes[1];
    int n_imgs = in_sizes[3] / 10;
    int n_pts  = in_sizes[4] / 3;

    size_t need = (size_t)n_pts * 16;

    if (ws_size >= need && n_imgs <= NCAM_MAX) {
        float4* pts4 = (float4*)d_ws;
        prep_pts<<<(n_pts + 255) / 256, 256, 0, stream>>>(pts3, pts4, n_pts);
        int block = 1024;
        int grid  = 512;   // 2 blocks/CU resident (LDS-limited), grid-stride
        reproj4_kernel<<<grid, block, 0, stream>>>(
            p2d, cidx, pidx, pose, pts4, (float*)d_out, M, n_imgs);
    } else {
        reproj_direct_kernel<<<(M + 255) / 256, 256, 0, stream>>>(
            (const float2*)p2d, cidx, pidx, pose, pts3, (float2*)d_out, M);
    }
}

// Round 6
// 96.907 us; speedup vs baseline: 1.2405x; 1.2405x over previous
//
#include <hip/hip_runtime.h>

// COLMAP reprojection residual.
// R4: pose-in-LDS 167->105us. R5: x4 unroll null at constant outstanding-reqs
// => per-CU MSHR x miss-latency throughput cap. R6 fix: fp16 point records
// (8B) -> 4MB table fits per-XCD 4MiB L2 -> gather latency ~3x lower.

typedef float  f2_t __attribute__((ext_vector_type(2)));
typedef _Float16 h4_t __attribute__((ext_vector_type(4)));

#define NCAM_MAX 2032   // 8 arrays * 2032 * 4B = 63.5 KB static LDS
#define UNROLL 4

__global__ __launch_bounds__(256) void prep_pts_h(
    const float* __restrict__ pts3, h4_t* __restrict__ ptsh, int n)
{
    int i = blockIdx.x * blockDim.x + threadIdx.x;
    if (i >= n) return;
    const float* p = pts3 + (long)i * 3;
    h4_t h;
    h.x = (_Float16)p[0];
    h.y = (_Float16)p[1];
    h.z = (_Float16)p[2];
    h.w = (_Float16)0.0f;
    ptsh[i] = h;
}

__device__ __forceinline__ void compute_one(
    float px, float py, float pz,
    float qx, float qy, float qz,
    float tx, float ty, float tz,
    float fl, unsigned kk,
    f2_t o, f2_t* r)
{
    float qw = sqrtf(fmaxf(0.0f, 1.0f - (qx*qx + qy*qy + qz*qz)));
    float ux = qy*pz - qz*py;
    float uy = qz*px - qx*pz;
    float uz = qx*py - qy*px;
    float wx = ux + qw*px;
    float wy = uy + qw*py;
    float wz = uz + qw*pz;
    float cx = qy*wz - qz*wy;
    float cy = qz*wx - qx*wz;
    float cz = qx*wy - qy*wx;
    float Px = px + 2.0f*cx + tx;
    float Py = py + 2.0f*cy + ty;
    float Pz = pz + 2.0f*cz + tz;
    float invz = 1.0f / Pz;
    float u = Px * invz;
    float v = Py * invz;
    float k1 = __uint_as_float(kk << 16);
    float k2 = __uint_as_float(kk & 0xffff0000u);
    float n = u*u + v*v;
    float d = 1.0f + k1*n + k2*n*n;
    float s = d * fl;
    r->x = u*s - o.x;
    r->y = v*s - o.y;
}

__global__ __launch_bounds__(1024) void reproj5_kernel(
    const float* __restrict__ p2d,
    const int* __restrict__ cidx,
    const int* __restrict__ pidx,
    const float* __restrict__ pose,
    const h4_t* __restrict__ ptsh,
    float* __restrict__ out,
    int M, int n_imgs)
{
    __shared__ float s_tx[NCAM_MAX], s_ty[NCAM_MAX], s_tz[NCAM_MAX];
    __shared__ float s_qx[NCAM_MAX], s_qy[NCAM_MAX], s_qz[NCAM_MAX];
    __shared__ float s_fl[NCAM_MAX];
    __shared__ unsigned s_kk[NCAM_MAX];

    for (int r = threadIdx.x; r < n_imgs; r += blockDim.x) {
        const float* c = pose + (long)r * 10;
        float tx = c[0], ty = c[1], tz = c[2];
        float qx = c[3], qy = c[4], qz = c[5], qw = c[6];
        float fl = c[7], k1 = c[8], k2 = c[9];
        float inv = rsqrtf(qx*qx + qy*qy + qz*qz + qw*qw);
        if (qw < 0.0f) inv = -inv;
        qx *= inv; qy *= inv; qz *= inv;
        s_tx[r] = tx; s_ty[r] = ty; s_tz[r] = tz;
        s_qx[r] = qx; s_qy[r] = qy; s_qz[r] = qz;
        s_fl[r] = fl;
        unsigned b1 = (__float_as_uint(k1) + 0x8000u) >> 16;
        unsigned b2 = (__float_as_uint(k2) + 0x8000u) >> 16;
        s_kk[r] = (b1 & 0xffffu) | ((b2 & 0xffffu) << 16);
    }
    __syncthreads();

    int tid = blockIdx.x * blockDim.x + threadIdx.x;
    int stride = gridDim.x * blockDim.x;
    long step = (long)stride * UNROLL;

    for (long base = tid; base < M; base += step) {
        if (base + (long)(UNROLL - 1) * stride < M) {
            int ci[UNROLL], pi[UNROLL];
            #pragma unroll
            for (int k = 0; k < UNROLL; k++) {
                long i = base + (long)k * stride;
                ci[k] = __builtin_nontemporal_load(cidx + i);
                pi[k] = __builtin_nontemporal_load(pidx + i);
            }
            h4_t p[UNROLL];
            f2_t o[UNROLL];
            #pragma unroll
            for (int k = 0; k < UNROLL; k++) {
                p[k] = ptsh[pi[k]];    // 8B L2-resident gather
                o[k] = __builtin_nontemporal_load((const f2_t*)p2d + (base + (long)k * stride));
            }
            #pragma unroll
            for (int k = 0; k < UNROLL; k++) {
                int c = ci[k];
                f2_t r;
                compute_one((float)p[k].x, (float)p[k].y, (float)p[k].z,
                            s_qx[c], s_qy[c], s_qz[c],
                            s_tx[c], s_ty[c], s_tz[c],
                            s_fl[c], s_kk[c], o[k], &r);
                __builtin_nontemporal_store(r, (f2_t*)out + (base + (long)k * stride));
            }
        } else {
            for (int k = 0; k < UNROLL; k++) {
                long i = base + (long)k * stride;
                if (i >= M) break;
                int c = __builtin_nontemporal_load(cidx + i);
                int pi1 = __builtin_nontemporal_load(pidx + i);
                h4_t p = ptsh[pi1];
                f2_t o = __builtin_nontemporal_load((const f2_t*)p2d + i);
                f2_t r;
                compute_one((float)p.x, (float)p.y, (float)p.z,
                            s_qx[c], s_qy[c], s_qz[c],
                            s_tx[c], s_ty[c], s_tz[c],
                            s_fl[c], s_kk[c], o, &r);
                __builtin_nontemporal_store(r, (f2_t*)out + i);
            }
        }
    }
}

// Fallback: direct per-obs kernel (ws too small or too many cameras).
__global__ __launch_bounds__(256) void reproj_direct_kernel(
    const float2* __restrict__ p2d,
    const int* __restrict__ cidx,
    const int* __restrict__ pidx,
    const float* __restrict__ pose,
    const float* __restrict__ pts3,
    float2* __restrict__ out,
    int M)
{
    int i = blockIdx.x * blockDim.x + threadIdx.x;
    if (i >= M) return;
    int ci = cidx[i];
    int pi = pidx[i];
    const float* cam = pose + (long)ci * 10;
    float tx = cam[0], ty = cam[1], tz = cam[2];
    float qx = cam[3], qy = cam[4], qz = cam[5], qw = cam[6];
    float f  = cam[7], k1 = cam[8], k2 = cam[9];
    float inv = rsqrtf(qx*qx + qy*qy + qz*qz + qw*qw);
    qx *= inv; qy *= inv; qz *= inv; qw *= inv;
    const float* pp = pts3 + (long)pi * 3;
    float px = pp[0], py = pp[1], pz = pp[2];
    float ux = qy*pz - qz*py;
    float uy = qz*px - qx*pz;
    float uz = qx*py - qy*px;
    float wx = ux + qw*px;
    float wy = uy + qw*py;
    float wz = uz + qw*pz;
    float cx = qy*wz - qz*wy;
    float cy = qz*wx - qx*wz;
    float cz = qx*wy - qy*wx;
    float Px = px + 2.0f*cx + tx;
    float Py = py + 2.0f*cy + ty;
    float Pz = pz + 2.0f*cz + tz;
    float invz = 1.0f / Pz;
    float u = Px * invz;
    float v = Py * invz;
    float n = u*u + v*v;
    float d = 1.0f + k1*n + k2*n*n;
    float s = d * f;
    float2 o = p2d[i];
    out[i] = make_float2(u*s - o.x, v*s - o.y);
}

extern "C" void kernel_launch(void* const* d_in, const int* in_sizes, int n_in,
                              void* d_out, int out_size, void* d_ws, size_t ws_size,
                              hipStream_t stream) {
    const float* p2d  = (const float*)d_in[0];
    const int*   cidx = (const int*)d_in[1];
    const int*   pidx = (const int*)d_in[2];
    const float* pose = (const float*)d_in[3];
    const float* pts3 = (const float*)d_in[4];

    int M      = in_sizes[1];
    int n_imgs = in_sizes[3] / 10;
    int n_pts  = in_sizes[4] / 3;

    size_t need = (size_t)n_pts * 8;

    if (ws_size >= need && n_imgs <= NCAM_MAX) {
        h4_t* ptsh = (h4_t*)d_ws;
        prep_pts_h<<<(n_pts + 255) / 256, 256, 0, stream>>>(pts3, ptsh, n_pts);
        int block = 1024;
        int grid  = 512;   // LDS-limited 2 blocks/CU, grid-stride
        reproj5_kernel<<<grid, block, 0, stream>>>(
            p2d, cidx, pidx, pose, ptsh, (float*)d_out, M, n_imgs);
    } else {
        reproj_direct_kernel<<<(M + 255) / 256, 256, 0, stream>>>(
            (const float2*)p2d, cidx, pidx, pose, pts3, (float2*)d_out, M);
    }
}